// Round 2
// baseline (711.180 us; speedup 1.0000x reference)
//
#include <hip/hip_runtime.h>

// RegimeAwareStudent: B=524288 tokens, ALL tensors fp32 (per reference), rid int32.
//   h  = relu(x @ fe_w1 + fe_b1)           [B,128]->[B,256]
//   f  = relu(h @ fe_w2 + fe_b2)           [B,256]->[B,128]
//   c  = concat(f, emb[rid])               [B,192]
//   eh = relu(c @ ew1[rid] + eb1[rid])     [B,192]->[B,256]
//   o  = eh @ ew2[rid] + eb2[rid]          [B,256]->[B,1]
// bf16 MFMA path (RNE at staging), fp32 accumulate, fp32 out.
// R2 vs R1 (247.6us fused, occupancy-starved at ~2.5 blocks/CU):
//   * LDS = exactly 32768B: stride-256 tile + XOR swizzle ((row&7)<<4) instead
//     of pad; perm/bounds in registers (per-wave ballot sort + ds_permute);
//     reduction scratch overlays unused C-tile cols [192,256). => 5 blocks/CU.
//   * __launch_bounds__(256,5) (102-reg unified budget). Stage-3 restructured
//     kt-outer with static tile-count switch: B-frags loaded once per regime
//     WITHOUT 96 resident AGPRs (R1's hoist killed occupancy). Stage-1 split
//     into two nn-halves with packed-bf16 stash across the barrier.
//   * X staged unsorted (token space); permutation applied at stage-2 F-write
//     via ds_bpermute => x loads issue at kernel start, not behind the sort.

typedef short short8 __attribute__((ext_vector_type(8)));
typedef float f32x4  __attribute__((ext_vector_type(4)));

#define MFMA16 __builtin_amdgcn_mfma_f32_16x16x32_bf16

constexpr int B_TOK  = 524288;
constexpr int TM     = 64;                 // tokens per tile
constexpr int NTILES = B_TOK / TM;         // 8192, exact

// packed-weight layout in d_ws (ushort element offsets)
constexpr size_t PW1_OFF   = 0;            // fe_w1: 4kt*16nt*64lane*8 = 32768 el
constexpr size_t PW2_OFF   = 32768;        // fe_w2: 8kt*8nt*64*8      = 32768 el
constexpr size_t PE1_OFF   = 65536;        // ew1:   3 * 6kt*16nt*64*8 = 147456 el
constexpr size_t PE1_PER_R = 49152;
// total ws = 212992 ushort = 425,984 bytes

static __device__ __forceinline__ ushort f2bf(float f) {  // RNE (repack only)
    union { float f; unsigned int i; } x; x.f = f;
    unsigned int i = x.i;
    i += 0x7fffu + ((i >> 16) & 1u);
    return (ushort)(i >> 16);
}

// HW packed f32->bf16 (RNE): D[15:0]=bf16(lo), D[31:16]=bf16(hi)
static __device__ __forceinline__ unsigned pk_bf16(float lo, float hi) {
    unsigned r;
    asm("v_cvt_pk_bf16_f32 %0, %1, %2" : "=v"(r) : "v"(lo), "v"(hi));
    return r;
}

static __device__ __forceinline__ short8 pack8(f32x4 f0, f32x4 f1) {
    union { unsigned u[4]; short8 s; } r;
    r.u[0] = pk_bf16(f0[0], f0[1]);
    r.u[1] = pk_bf16(f0[2], f0[3]);
    r.u[2] = pk_bf16(f1[0], f1[1]);
    r.u[3] = pk_bf16(f1[2], f1[3]);
    return r.s;
}

// swizzled byte offset into the [64][256]-ushort tile (row stride 512B).
// XOR of byte bits 4-6 with row&7: b128 reads at fixed column spread 16
// consecutive rows across all 8 bank groups (2-way max aliasing = free).
static __device__ __forceinline__ int swz(int row, int inb) {
    return (row * 512 + inb) ^ ((row & 7) << 4);
}

// ---- weight repack: fp32 -> bf16 MFMA B-fragment layout -------------------
// pw[frag=kt*NT+nt][lane][j] = bf16(W[kt*32 + (lane>>4)*8 + j][nt*16 + (lane&15)])
__global__ void repack_weights(const float* __restrict__ w1,
                               const float* __restrict__ w2,
                               const float* __restrict__ e1,
                               ushort* __restrict__ pw) {
    int t = blockIdx.x * 256 + threadIdx.x;       // 26624 threads total
    const float* src; int N, kt, nt; size_t dst;
    int lane = t & 63;
    if (t < 4096) {                                // fe_w1: K=128,N=256
        int frag = t >> 6; kt = frag >> 4; nt = frag & 15;
        src = w1; N = 256; dst = PW1_OFF + (size_t)t * 8;
    } else if (t < 8192) {                         // fe_w2: K=256,N=128
        int u = t - 4096; int frag = u >> 6; kt = frag >> 3; nt = frag & 7;
        src = w2; N = 128; dst = PW2_OFF + (size_t)u * 8;
    } else {                                       // ew1[r]: K=192,N=256
        int u = t - 8192; int reg = u / 6144; int v = u % 6144;
        int frag = v >> 6; kt = frag >> 4; nt = frag & 15;
        src = e1 + (size_t)reg * (192 * 256); N = 256;
        dst = PE1_OFF + (size_t)reg * PE1_PER_R + (size_t)v * 8;
    }
    int quad = lane >> 4, cc = lane & 15;
    int k0 = kt * 32 + quad * 8;
    int n  = nt * 16 + cc;
    short8 vv;
    #pragma unroll
    for (int j = 0; j < 8; ++j) vv[j] = (short)f2bf(src[(size_t)(k0 + j) * N + n]);
    *(short8*)(pw + dst) = vv;
}

// stage-3 body for a compile-time tile count NT: B-frags loaded once per kt
// (so once per regime overall), accumulators for all NT tiles held statically.
#define STAGE3_TILES(NT)                                                        \
    {                                                                           \
        f32x4 acc[NT][4] = {};                                                  \
        _Pragma("unroll")                                                       \
        for (int kt = 0; kt < 6; ++kt) {                                        \
            short8 bfr[4];                                                      \
            _Pragma("unroll")                                                   \
            for (int nn = 0; nn < 4; ++nn)                                      \
                bfr[nn] = *(const short8*)(pe +                                 \
                        ((size_t)((kt * 16 + (w * 4 + nn)) * 64 + lane)) * 8);  \
            _Pragma("unroll")                                                   \
            for (int tt = 0; tt < NT; ++tt) {                                   \
                int row = (mlo + tt) * 16 + c;                                  \
                short8 a = *(const short8*)((const char*)sBuf +                 \
                        swz(row, kt * 64 + quad * 16));                         \
                _Pragma("unroll")                                               \
                for (int nn = 0; nn < 4; ++nn)                                  \
                    acc[tt][nn] = MFMA16(a, bfr[nn], acc[tt][nn], 0, 0, 0);     \
            }                                                                   \
        }                                                                       \
        _Pragma("unroll")                                                       \
        for (int tt = 0; tt < NT; ++tt) {                                       \
            float s[4] = {0.f, 0.f, 0.f, 0.f};                                  \
            _Pragma("unroll")                                                   \
            for (int nn = 0; nn < 4; ++nn)                                      \
                _Pragma("unroll")                                               \
                for (int i = 0; i < 4; ++i)                                     \
                    s[i] += fmaxf(acc[tt][nn][i] + eb1v[nn], 0.0f) * w2v[nn];   \
            _Pragma("unroll")                                                   \
            for (int i = 0; i < 4; ++i) {                                       \
                s[i] += __shfl_xor(s[i], 1);                                    \
                s[i] += __shfl_xor(s[i], 2);                                    \
                s[i] += __shfl_xor(s[i], 4);                                    \
                s[i] += __shfl_xor(s[i], 8);                                    \
            }                                                                   \
            if (c == 0) {                                                       \
                _Pragma("unroll")                                               \
                for (int i = 0; i < 4; ++i) {                                   \
                    int row = (mlo + tt) * 16 + quad * 4 + i;                   \
                    if (row >= lo && row < hi)                                  \
                        *(float*)((char*)sBuf + swz(row, 384) + w * 4) = s[i];  \
                }                                                               \
            }                                                                   \
        }                                                                       \
    }

// ---- fused main: 64 consecutive tokens, in-register regime sort, full MLP --
__global__ __launch_bounds__(256, 5) void fused_main(
    const float* __restrict__ x,
    const int*   __restrict__ rid,
    const ushort* __restrict__ pw,
    const float* __restrict__ fe_b1,
    const float* __restrict__ fe_b2,
    const float* __restrict__ emb,
    const float* __restrict__ eb1,
    const float* __restrict__ ew2,
    const float* __restrict__ eb2,
    float*       __restrict__ out) {
    __shared__ ushort sBuf[64 * 256];  // exactly 32768 B => 5 blocks/CU

    const int t    = threadIdx.x;
    const int w    = t >> 6;
    const int lane = t & 63;
    const int quad = lane >> 4;
    const int c    = lane & 15;
    const int ts   = blockIdx.x * TM;

    // ---- stage X into LDS, UNSORTED (token rows), swizzled ----
    // issued immediately; independent of the sort below.
    #pragma unroll
    for (int it = 0; it < 4; ++it) {
        int chunk = it * 256 + t;
        int row = chunk >> 4, seg = chunk & 15;   // 8 floats per chunk
        const float* xr = x + (size_t)(ts + row) * 128 + seg * 8;
        f32x4 f0 = *(const f32x4*)xr;
        f32x4 f1 = *(const f32x4*)(xr + 4);
        *(short8*)((char*)sBuf + swz(row, seg * 16)) = pack8(f0, f1);
    }

    // ---- per-wave (redundant, uniform) counting sort of the 64 tokens ----
    // lane l = token l. slot = sorted position of token l. b1/b2 = bounds.
    int slot, b1, b2, tos;
    {
        int myr = rid[ts + lane];
        unsigned long long below = (1ull << lane) - 1ull;
        int base = 0, bb1 = 0, bb2 = 0;
        slot = 0;
        #pragma unroll
        for (int r = 0; r < 3; ++r) {
            unsigned long long mask = __ballot(myr == r);
            if (myr == r) slot = base + __popcll(mask & below);
            base += __popcll(mask);
            if (r == 0) bb1 = base;
            if (r == 1) bb2 = base;
        }
        b1 = __builtin_amdgcn_readfirstlane(bb1);
        b2 = __builtin_amdgcn_readfirstlane(bb2);
        // inverse perm: lane s receives token index whose slot == s
        tos = __builtin_amdgcn_ds_permute(slot << 2, lane);
    }
    __syncthreads();   // X visible to all waves

    // ---- stage 1: H = relu(X @ W1 + b1), token space; two nn-halves ----
    // packed-bf16 stash across the reuse barrier keeps peak regs low.
    unsigned hpk[2][16];
    #pragma unroll
    for (int half = 0; half < 2; ++half) {
        f32x4 acc[4][2] = {};
        #pragma unroll
        for (int kt = 0; kt < 4; ++kt) {
            short8 a[4], b[2];
            #pragma unroll
            for (int m = 0; m < 4; ++m) {
                int row = m * 16 + c;
                a[m] = *(const short8*)((const char*)sBuf +
                        swz(row, kt * 64 + quad * 16));
            }
            #pragma unroll
            for (int nn = 0; nn < 2; ++nn)
                b[nn] = *(const short8*)(pw + PW1_OFF +
                        ((size_t)((kt * 16 + (w * 4 + half * 2 + nn)) * 64 + lane)) * 8);
            #pragma unroll
            for (int m = 0; m < 4; ++m)
                #pragma unroll
                for (int nn = 0; nn < 2; ++nn)
                    acc[m][nn] = MFMA16(a[m], b[nn], acc[m][nn], 0, 0, 0);
        }
        #pragma unroll
        for (int nn = 0; nn < 2; ++nn) {
            float bb = fe_b1[w * 64 + (half * 2 + nn) * 16 + c];
            #pragma unroll
            for (int m = 0; m < 4; ++m) {
                float v0 = fmaxf(acc[m][nn][0] + bb, 0.0f);
                float v1 = fmaxf(acc[m][nn][1] + bb, 0.0f);
                float v2 = fmaxf(acc[m][nn][2] + bb, 0.0f);
                float v3 = fmaxf(acc[m][nn][3] + bb, 0.0f);
                hpk[half][(m * 2 + nn) * 2 + 0] = pk_bf16(v0, v1);
                hpk[half][(m * 2 + nn) * 2 + 1] = pk_bf16(v2, v3);
            }
        }
    }
    __syncthreads();   // all waves done reading X

    #pragma unroll
    for (int half = 0; half < 2; ++half)
        #pragma unroll
        for (int m = 0; m < 4; ++m)
            #pragma unroll
            for (int nn = 0; nn < 2; ++nn) {
                int col = w * 64 + (half * 2 + nn) * 16 + c;
                int r0  = m * 16 + quad * 4;
                unsigned p01 = hpk[half][(m * 2 + nn) * 2 + 0];
                unsigned p23 = hpk[half][(m * 2 + nn) * 2 + 1];
                *(ushort*)((char*)sBuf + swz(r0 + 0, col * 2)) = (ushort)p01;
                *(ushort*)((char*)sBuf + swz(r0 + 1, col * 2)) = (ushort)(p01 >> 16);
                *(ushort*)((char*)sBuf + swz(r0 + 2, col * 2)) = (ushort)p23;
                *(ushort*)((char*)sBuf + swz(r0 + 3, col * 2)) = (ushort)(p23 >> 16);
            }
    __syncthreads();   // H visible

    // ---- stage 2: F = relu(H @ W2 + b2), token space ----
    f32x4 acc2[4][2] = {};
    #pragma unroll
    for (int kt = 0; kt < 8; ++kt) {
        short8 a[4], b[2];
        #pragma unroll
        for (int m = 0; m < 4; ++m) {
            int row = m * 16 + c;
            a[m] = *(const short8*)((const char*)sBuf +
                    swz(row, kt * 64 + quad * 16));
        }
        #pragma unroll
        for (int nn = 0; nn < 2; ++nn)
            b[nn] = *(const short8*)(pw + PW2_OFF +
                    ((size_t)((kt * 8 + (w * 2 + nn)) * 64 + lane)) * 8);
        #pragma unroll
        for (int m = 0; m < 4; ++m)
            #pragma unroll
            for (int nn = 0; nn < 2; ++nn)
                acc2[m][nn] = MFMA16(a[m], b[nn], acc2[m][nn], 0, 0, 0);
    }
    __syncthreads();   // all waves done reading H

    // F-write: token-space results scattered to SLOT rows (ds_bpermute gives
    // slotOfToken). Downstream stage-3 reads are then regular/conflict-free.
    {
        float b2v[2];
        #pragma unroll
        for (int nn = 0; nn < 2; ++nn) b2v[nn] = fe_b2[w * 32 + nn * 16 + c];
        #pragma unroll
        for (int m = 0; m < 4; ++m) {
            int sr[4];
            #pragma unroll
            for (int i = 0; i < 4; ++i)
                sr[i] = __builtin_amdgcn_ds_bpermute((m * 16 + quad * 4 + i) << 2, slot);
            #pragma unroll
            for (int nn = 0; nn < 2; ++nn) {
                int col = w * 32 + nn * 16 + c;
                float v0 = fmaxf(acc2[m][nn][0] + b2v[nn], 0.0f);
                float v1 = fmaxf(acc2[m][nn][1] + b2v[nn], 0.0f);
                float v2 = fmaxf(acc2[m][nn][2] + b2v[nn], 0.0f);
                float v3 = fmaxf(acc2[m][nn][3] + b2v[nn], 0.0f);
                unsigned p01 = pk_bf16(v0, v1);
                unsigned p23 = pk_bf16(v2, v3);
                *(ushort*)((char*)sBuf + swz(sr[0], col * 2)) = (ushort)p01;
                *(ushort*)((char*)sBuf + swz(sr[1], col * 2)) = (ushort)(p01 >> 16);
                *(ushort*)((char*)sBuf + swz(sr[2], col * 2)) = (ushort)p23;
                *(ushort*)((char*)sBuf + swz(sr[3], col * 2)) = (ushort)(p23 >> 16);
            }
        }
    }
    // append per-slot-row regime embedding to C cols [128,192)
    #pragma unroll
    for (int it = 0; it < 2; ++it) {
        int chunk = it * 256 + t;
        int row = chunk >> 3, seg = chunk & 7;    // slot rows
        int rr = (row >= b1) + (row >= b2);
        const float* ep = emb + rr * 64 + seg * 8;
        f32x4 f0 = *(const f32x4*)ep;
        f32x4 f1 = *(const f32x4*)(ep + 4);
        *(short8*)((char*)sBuf + swz(row, 256 + seg * 16)) = pack8(f0, f1);
    }
    __syncthreads();   // C visible (slot space)

    // ---- stage 3: per regime, kt-outer over its m-tiles (static count) ----
    // reduction partials overlay the unused C cols [192,256): float red[64][4].
    for (int r = 0; r < 3; ++r) {
        int lo = (r == 0) ? 0  : (r == 1 ? b1 : b2);
        int hi = (r == 0) ? b1 : (r == 1 ? b2 : 64);
        if (lo >= hi) continue;               // block-uniform
        const ushort* pe = pw + PE1_OFF + (size_t)r * PE1_PER_R;
        float eb1v[4], w2v[4];
        #pragma unroll
        for (int nn = 0; nn < 4; ++nn) {
            int col = w * 64 + nn * 16 + c;
            eb1v[nn] = eb1[r * 256 + col];
            w2v[nn]  = ew2[r * 256 + col];
        }
        int mlo = lo >> 4, mhi = (hi - 1) >> 4;
        switch (mhi - mlo) {
            case 0:  STAGE3_TILES(1); break;
            case 1:  STAGE3_TILES(2); break;
            case 2:  STAGE3_TILES(3); break;
            default: STAGE3_TILES(4); break;
        }
    }
    __syncthreads();

    // ---- final: sum 4 wave-partials + eb2[regime], scatter fp32 out ----
    if (t < 64) {                              // wave 0: lane t = slot t
        int rr = (t >= b1) + (t >= b2);
        f32x4 rv = *(const f32x4*)((const char*)sBuf + swz(t, 384));
        out[ts + tos] = rv[0] + rv[1] + rv[2] + rv[3] + eb2[rr];
    }
}

extern "C" void kernel_launch(void* const* d_in, const int* in_sizes, int n_in,
                              void* d_out, int out_size, void* d_ws, size_t ws_size,
                              hipStream_t stream) {
    const float* x     = (const float*)d_in[0];
    const int*   rid   = (const int*)d_in[1];
    const float* fe_w1 = (const float*)d_in[2];
    const float* fe_b1 = (const float*)d_in[3];
    const float* fe_w2 = (const float*)d_in[4];
    const float* fe_b2 = (const float*)d_in[5];
    const float* emb   = (const float*)d_in[6];
    const float* ew1   = (const float*)d_in[7];
    const float* eb1   = (const float*)d_in[8];
    const float* ew2   = (const float*)d_in[9];
    const float* eb2   = (const float*)d_in[10];
    float* out = (float*)d_out;
    ushort* pw = (ushort*)d_ws;   // 425,984 bytes used

    hipLaunchKernelGGL(repack_weights, dim3(104), dim3(256), 0, stream,
                       fe_w1, fe_w2, ew1, pw);
    hipLaunchKernelGGL(fused_main, dim3(NTILES), dim3(256), 0, stream,
                       x, rid, pw, fe_b1, fe_b2, emb, eb1, ew2, eb2, out);
}

// Round 3
// 675.803 us; speedup vs baseline: 1.0523x; 1.0523x over previous
//
#include <hip/hip_runtime.h>

// RegimeAwareStudent: B=524288 tokens, ALL tensors fp32 (per reference), rid int32.
//   h  = relu(x @ fe_w1 + fe_b1)           [B,128]->[B,256]
//   f  = relu(h @ fe_w2 + fe_b2)           [B,256]->[B,128]
//   c  = concat(f, emb[rid])               [B,192]
//   eh = relu(c @ ew1[rid] + eb1[rid])     [B,192]->[B,256]
//   o  = eh @ ew2[rid] + eb2[rid]          [B,256]->[B,1]
// bf16 MFMA path (RNE at staging), fp32 accumulate, fp32 out.
// R3 vs R2 (456us: launch_bounds(256,5)=102 regs forced 654MB of scratch
// spills) and R1 (247us: 96-AGPR stage-3 hoist capped occupancy at ~10 waves):
//   * __launch_bounds__(256,4) = 128 unified regs. Peak live kept ~112 by
//     construction: two-half stage 1 with packed stash, simple per-m-tile
//     stage 3 (acc[4] only; B-frags re-read per tile from L2 - they are
//     L2-resident and latency-hidden at 4 blocks/CU). NO spills.
//   * LDS stays 32768B (swizzled single buffer) -> LDS allows 5 blocks/CU,
//     regs cap at 4 blocks/CU = 16 waves = 50% occupancy.

typedef short short8 __attribute__((ext_vector_type(8)));
typedef float f32x4  __attribute__((ext_vector_type(4)));

#define MFMA16 __builtin_amdgcn_mfma_f32_16x16x32_bf16

constexpr int B_TOK  = 524288;
constexpr int TM     = 64;                 // tokens per tile
constexpr int NTILES = B_TOK / TM;         // 8192, exact

// packed-weight layout in d_ws (ushort element offsets)
constexpr size_t PW1_OFF   = 0;            // fe_w1: 4kt*16nt*64lane*8 = 32768 el
constexpr size_t PW2_OFF   = 32768;        // fe_w2: 8kt*8nt*64*8      = 32768 el
constexpr size_t PE1_OFF   = 65536;        // ew1:   3 * 6kt*16nt*64*8 = 147456 el
constexpr size_t PE1_PER_R = 49152;
// total ws = 212992 ushort = 425,984 bytes

static __device__ __forceinline__ ushort f2bf(float f) {  // RNE (repack only)
    union { float f; unsigned int i; } x; x.f = f;
    unsigned int i = x.i;
    i += 0x7fffu + ((i >> 16) & 1u);
    return (ushort)(i >> 16);
}

// HW packed f32->bf16 (RNE): D[15:0]=bf16(lo), D[31:16]=bf16(hi)
static __device__ __forceinline__ unsigned pk_bf16(float lo, float hi) {
    unsigned r;
    asm("v_cvt_pk_bf16_f32 %0, %1, %2" : "=v"(r) : "v"(lo), "v"(hi));
    return r;
}

static __device__ __forceinline__ short8 pack8(f32x4 f0, f32x4 f1) {
    union { unsigned u[4]; short8 s; } r;
    r.u[0] = pk_bf16(f0[0], f0[1]);
    r.u[1] = pk_bf16(f0[2], f0[3]);
    r.u[2] = pk_bf16(f1[0], f1[1]);
    r.u[3] = pk_bf16(f1[2], f1[3]);
    return r.s;
}

// swizzled byte offset into the [64][256]-ushort tile (row stride 512B).
// XOR of byte bits 4-6 with row&7: b128 reads at fixed column spread 16
// consecutive rows across all 8 bank groups (2-way max aliasing = free).
static __device__ __forceinline__ int swz(int row, int inb) {
    return (row * 512 + inb) ^ ((row & 7) << 4);
}

// ---- weight repack: fp32 -> bf16 MFMA B-fragment layout -------------------
// pw[frag=kt*NT+nt][lane][j] = bf16(W[kt*32 + (lane>>4)*8 + j][nt*16 + (lane&15)])
__global__ void repack_weights(const float* __restrict__ w1,
                               const float* __restrict__ w2,
                               const float* __restrict__ e1,
                               ushort* __restrict__ pw) {
    int t = blockIdx.x * 256 + threadIdx.x;       // 26624 threads total
    const float* src; int N, kt, nt; size_t dst;
    int lane = t & 63;
    if (t < 4096) {                                // fe_w1: K=128,N=256
        int frag = t >> 6; kt = frag >> 4; nt = frag & 15;
        src = w1; N = 256; dst = PW1_OFF + (size_t)t * 8;
    } else if (t < 8192) {                         // fe_w2: K=256,N=128
        int u = t - 4096; int frag = u >> 6; kt = frag >> 3; nt = frag & 7;
        src = w2; N = 128; dst = PW2_OFF + (size_t)u * 8;
    } else {                                       // ew1[r]: K=192,N=256
        int u = t - 8192; int reg = u / 6144; int v = u % 6144;
        int frag = v >> 6; kt = frag >> 4; nt = frag & 15;
        src = e1 + (size_t)reg * (192 * 256); N = 256;
        dst = PE1_OFF + (size_t)reg * PE1_PER_R + (size_t)v * 8;
    }
    int quad = lane >> 4, cc = lane & 15;
    int k0 = kt * 32 + quad * 8;
    int n  = nt * 16 + cc;
    short8 vv;
    #pragma unroll
    for (int j = 0; j < 8; ++j) vv[j] = (short)f2bf(src[(size_t)(k0 + j) * N + n]);
    *(short8*)(pw + dst) = vv;
}

// ---- fused main: 64 consecutive tokens, in-register regime sort, full MLP --
__global__ __launch_bounds__(256, 4) void fused_main(
    const float* __restrict__ x,
    const int*   __restrict__ rid,
    const ushort* __restrict__ pw,
    const float* __restrict__ fe_b1,
    const float* __restrict__ fe_b2,
    const float* __restrict__ emb,
    const float* __restrict__ eb1,
    const float* __restrict__ ew2,
    const float* __restrict__ eb2,
    float*       __restrict__ out) {
    __shared__ ushort sBuf[64 * 256];  // exactly 32768 B

    const int t    = threadIdx.x;
    const int w    = t >> 6;
    const int lane = t & 63;
    const int quad = lane >> 4;
    const int c    = lane & 15;
    const int ts   = blockIdx.x * TM;

    // ---- stage X into LDS, UNSORTED (token rows), swizzled ----
    // issued immediately; independent of the sort below.
    #pragma unroll
    for (int it = 0; it < 4; ++it) {
        int chunk = it * 256 + t;
        int row = chunk >> 4, seg = chunk & 15;   // 8 floats per chunk
        const float* xr = x + (size_t)(ts + row) * 128 + seg * 8;
        f32x4 f0 = *(const f32x4*)xr;
        f32x4 f1 = *(const f32x4*)(xr + 4);
        *(short8*)((char*)sBuf + swz(row, seg * 16)) = pack8(f0, f1);
    }

    // ---- per-wave (redundant, uniform) counting sort of the 64 tokens ----
    // lane l = token l. slot = sorted position of token l. b1/b2 = bounds.
    int slot, b1, b2, tos;
    {
        int myr = rid[ts + lane];
        unsigned long long below = (1ull << lane) - 1ull;
        int base = 0, bb1 = 0, bb2 = 0;
        slot = 0;
        #pragma unroll
        for (int r = 0; r < 3; ++r) {
            unsigned long long mask = __ballot(myr == r);
            if (myr == r) slot = base + __popcll(mask & below);
            base += __popcll(mask);
            if (r == 0) bb1 = base;
            if (r == 1) bb2 = base;
        }
        b1 = __builtin_amdgcn_readfirstlane(bb1);
        b2 = __builtin_amdgcn_readfirstlane(bb2);
        // inverse perm: lane s receives token index whose slot == s
        tos = __builtin_amdgcn_ds_permute(slot << 2, lane);
    }
    __syncthreads();   // X visible to all waves

    // ---- stage 1: H = relu(X @ W1 + b1), token space; two nn-halves ----
    // packed-bf16 stash across the reuse barrier keeps peak regs ~112.
    unsigned hpk[2][16];
    #pragma unroll
    for (int half = 0; half < 2; ++half) {
        f32x4 acc[4][2] = {};
        #pragma unroll
        for (int kt = 0; kt < 4; ++kt) {
            short8 a[4], b[2];
            #pragma unroll
            for (int m = 0; m < 4; ++m) {
                int row = m * 16 + c;
                a[m] = *(const short8*)((const char*)sBuf +
                        swz(row, kt * 64 + quad * 16));
            }
            #pragma unroll
            for (int nn = 0; nn < 2; ++nn)
                b[nn] = *(const short8*)(pw + PW1_OFF +
                        ((size_t)((kt * 16 + (w * 4 + half * 2 + nn)) * 64 + lane)) * 8);
            #pragma unroll
            for (int m = 0; m < 4; ++m)
                #pragma unroll
                for (int nn = 0; nn < 2; ++nn)
                    acc[m][nn] = MFMA16(a[m], b[nn], acc[m][nn], 0, 0, 0);
        }
        #pragma unroll
        for (int nn = 0; nn < 2; ++nn) {
            float bb = fe_b1[w * 64 + (half * 2 + nn) * 16 + c];
            #pragma unroll
            for (int m = 0; m < 4; ++m) {
                float v0 = fmaxf(acc[m][nn][0] + bb, 0.0f);
                float v1 = fmaxf(acc[m][nn][1] + bb, 0.0f);
                float v2 = fmaxf(acc[m][nn][2] + bb, 0.0f);
                float v3 = fmaxf(acc[m][nn][3] + bb, 0.0f);
                hpk[half][(m * 2 + nn) * 2 + 0] = pk_bf16(v0, v1);
                hpk[half][(m * 2 + nn) * 2 + 1] = pk_bf16(v2, v3);
            }
        }
    }
    __syncthreads();   // all waves done reading X

    #pragma unroll
    for (int half = 0; half < 2; ++half)
        #pragma unroll
        for (int m = 0; m < 4; ++m)
            #pragma unroll
            for (int nn = 0; nn < 2; ++nn) {
                int col = w * 64 + (half * 2 + nn) * 16 + c;
                int r0  = m * 16 + quad * 4;
                unsigned p01 = hpk[half][(m * 2 + nn) * 2 + 0];
                unsigned p23 = hpk[half][(m * 2 + nn) * 2 + 1];
                *(ushort*)((char*)sBuf + swz(r0 + 0, col * 2)) = (ushort)p01;
                *(ushort*)((char*)sBuf + swz(r0 + 1, col * 2)) = (ushort)(p01 >> 16);
                *(ushort*)((char*)sBuf + swz(r0 + 2, col * 2)) = (ushort)p23;
                *(ushort*)((char*)sBuf + swz(r0 + 3, col * 2)) = (ushort)(p23 >> 16);
            }
    __syncthreads();   // H visible

    // ---- stage 2: F = relu(H @ W2 + b2), token space ----
    f32x4 acc2[4][2] = {};
    #pragma unroll
    for (int kt = 0; kt < 8; ++kt) {
        short8 a[4], b[2];
        #pragma unroll
        for (int m = 0; m < 4; ++m) {
            int row = m * 16 + c;
            a[m] = *(const short8*)((const char*)sBuf +
                    swz(row, kt * 64 + quad * 16));
        }
        #pragma unroll
        for (int nn = 0; nn < 2; ++nn)
            b[nn] = *(const short8*)(pw + PW2_OFF +
                    ((size_t)((kt * 8 + (w * 2 + nn)) * 64 + lane)) * 8);
        #pragma unroll
        for (int m = 0; m < 4; ++m)
            #pragma unroll
            for (int nn = 0; nn < 2; ++nn)
                acc2[m][nn] = MFMA16(a[m], b[nn], acc2[m][nn], 0, 0, 0);
    }
    __syncthreads();   // all waves done reading H

    // F-write: token-space results scattered to SLOT rows (ds_bpermute gives
    // slotOfToken). Downstream stage-3 reads are then regular/conflict-free.
    {
        float b2v[2];
        #pragma unroll
        for (int nn = 0; nn < 2; ++nn) b2v[nn] = fe_b2[w * 32 + nn * 16 + c];
        #pragma unroll
        for (int m = 0; m < 4; ++m) {
            int sr[4];
            #pragma unroll
            for (int i = 0; i < 4; ++i)
                sr[i] = __builtin_amdgcn_ds_bpermute((m * 16 + quad * 4 + i) << 2, slot);
            #pragma unroll
            for (int nn = 0; nn < 2; ++nn) {
                int col = w * 32 + nn * 16 + c;
                float v0 = fmaxf(acc2[m][nn][0] + b2v[nn], 0.0f);
                float v1 = fmaxf(acc2[m][nn][1] + b2v[nn], 0.0f);
                float v2 = fmaxf(acc2[m][nn][2] + b2v[nn], 0.0f);
                float v3 = fmaxf(acc2[m][nn][3] + b2v[nn], 0.0f);
                unsigned p01 = pk_bf16(v0, v1);
                unsigned p23 = pk_bf16(v2, v3);
                *(ushort*)((char*)sBuf + swz(sr[0], col * 2)) = (ushort)p01;
                *(ushort*)((char*)sBuf + swz(sr[1], col * 2)) = (ushort)(p01 >> 16);
                *(ushort*)((char*)sBuf + swz(sr[2], col * 2)) = (ushort)p23;
                *(ushort*)((char*)sBuf + swz(sr[3], col * 2)) = (ushort)(p23 >> 16);
            }
        }
    }
    // append per-slot-row regime embedding to C cols [128,192)
    #pragma unroll
    for (int it = 0; it < 2; ++it) {
        int chunk = it * 256 + t;
        int row = chunk >> 3, seg = chunk & 7;    // slot rows
        int rr = (row >= b1) + (row >= b2);
        const float* ep = emb + rr * 64 + seg * 8;
        f32x4 f0 = *(const f32x4*)ep;
        f32x4 f1 = *(const f32x4*)(ep + 4);
        *(short8*)((char*)sBuf + swz(row, 256 + seg * 16)) = pack8(f0, f1);
    }
    __syncthreads();   // C visible (slot space)

    // ---- stage 3: per regime, simple per-m-tile passes ----
    // B-frags re-read per m-tile (L2-resident, 24 x 16B/lane per pass);
    // acc[4] keeps live regs small. Reduction partials overlay the unused
    // C cols [192,256): float red[64][4].
    for (int r = 0; r < 3; ++r) {
        int lo = (r == 0) ? 0  : (r == 1 ? b1 : b2);
        int hi = (r == 0) ? b1 : (r == 1 ? b2 : 64);
        if (lo >= hi) continue;               // block-uniform
        const ushort* pe = pw + PE1_OFF + (size_t)r * PE1_PER_R;
        float eb1v[4], w2v[4];
        #pragma unroll
        for (int nn = 0; nn < 4; ++nn) {
            int col = w * 64 + nn * 16 + c;
            eb1v[nn] = eb1[r * 256 + col];
            w2v[nn]  = ew2[r * 256 + col];
        }
        int mlo = lo >> 4, mhi = (hi - 1) >> 4;
        for (int m = mlo; m <= mhi; ++m) {    // block-uniform
            f32x4 acc[4] = {};
            #pragma unroll
            for (int kt = 0; kt < 6; ++kt) {
                short8 a = *(const short8*)((const char*)sBuf +
                        swz(m * 16 + c, kt * 64 + quad * 16));
                #pragma unroll
                for (int nn = 0; nn < 4; ++nn) {
                    short8 b = *(const short8*)(pe +
                            ((size_t)((kt * 16 + (w * 4 + nn)) * 64 + lane)) * 8);
                    acc[nn] = MFMA16(a, b, acc[nn], 0, 0, 0);
                }
            }
            float s[4] = {0.f, 0.f, 0.f, 0.f};
            #pragma unroll
            for (int nn = 0; nn < 4; ++nn)
                #pragma unroll
                for (int i = 0; i < 4; ++i)
                    s[i] += fmaxf(acc[nn][i] + eb1v[nn], 0.0f) * w2v[nn];
            #pragma unroll
            for (int i = 0; i < 4; ++i) {     // reduce over 16 cols (lane bits 0..3)
                s[i] += __shfl_xor(s[i], 1);
                s[i] += __shfl_xor(s[i], 2);
                s[i] += __shfl_xor(s[i], 4);
                s[i] += __shfl_xor(s[i], 8);
            }
            if (c == 0) {
                #pragma unroll
                for (int i = 0; i < 4; ++i) {
                    int row = m * 16 + quad * 4 + i;
                    if (row >= lo && row < hi)
                        *(float*)((char*)sBuf + swz(row, 384) + w * 4) = s[i];
                }
            }
        }
    }
    __syncthreads();

    // ---- final: sum 4 wave-partials + eb2[regime], scatter fp32 out ----
    if (t < 64) {                              // wave 0: lane t = slot t
        int rr = (t >= b1) + (t >= b2);
        f32x4 rv = *(const f32x4*)((const char*)sBuf + swz(t, 384));
        out[ts + tos] = rv[0] + rv[1] + rv[2] + rv[3] + eb2[rr];
    }
}

extern "C" void kernel_launch(void* const* d_in, const int* in_sizes, int n_in,
                              void* d_out, int out_size, void* d_ws, size_t ws_size,
                              hipStream_t stream) {
    const float* x     = (const float*)d_in[0];
    const int*   rid   = (const int*)d_in[1];
    const float* fe_w1 = (const float*)d_in[2];
    const float* fe_b1 = (const float*)d_in[3];
    const float* fe_w2 = (const float*)d_in[4];
    const float* fe_b2 = (const float*)d_in[5];
    const float* emb   = (const float*)d_in[6];
    const float* ew1   = (const float*)d_in[7];
    const float* eb1   = (const float*)d_in[8];
    const float* ew2   = (const float*)d_in[9];
    const float* eb2   = (const float*)d_in[10];
    float* out = (float*)d_out;
    ushort* pw = (ushort*)d_ws;   // 425,984 bytes used

    hipLaunchKernelGGL(repack_weights, dim3(104), dim3(256), 0, stream,
                       fe_w1, fe_w2, ew1, pw);
    hipLaunchKernelGGL(fused_main, dim3(NTILES), dim3(256), 0, stream,
                       x, rid, pw, fe_b1, fe_b2, emb, eb1, ew2, eb2, out);
}

// Round 4
// 527.723 us; speedup vs baseline: 1.3476x; 1.2806x over previous
//
#include <hip/hip_runtime.h>

// RegimeAwareStudent: B=524288 tokens, ALL tensors fp32 (per reference), rid int32.
//   h  = relu(x @ fe_w1 + fe_b1)           [B,128]->[B,256]
//   f  = relu(h @ fe_w2 + fe_b2)           [B,256]->[B,128]
//   c  = concat(f, emb[rid])               [B,192]
//   eh = relu(c @ ew1[rid] + eb1[rid])     [B,192]->[B,256]
//   o  = eh @ ew2[rid] + eb2[rid]          [B,256]->[B,1]
// bf16 MFMA path (RNE at staging), fp32 accumulate, fp32 out.
// R4: the 4-wave/64-col decomposition needs >128 regs (R2: 654MB spills at
// 102-reg cap; R3: 600MB spills at 128-reg cap; only non-spill point was R1
// at ~170 regs / 10 waves). Fix the DECOMPOSITION: 512 threads = 8 waves per
// 64-token tile, per-wave width halved everywhere:
//   stage1 acc[4][2]=32 regs (no stash - acc held across the reuse barrier),
//   stage2 acc[4]=16, stage3 acc[2]=8. Structural peak ~76 live regs ->
//   __launch_bounds__(512,4) (128-reg budget) is non-binding => no spills,
//   ~5-6 waves/SIMD (20-24 waves/CU) occupancy.
// LDS: 32KB swizzled single tile + 2KB dedicated sRed (LDS not binding).

typedef short short8 __attribute__((ext_vector_type(8)));
typedef float f32x4  __attribute__((ext_vector_type(4)));

#define MFMA16 __builtin_amdgcn_mfma_f32_16x16x32_bf16

constexpr int B_TOK  = 524288;
constexpr int TM     = 64;                 // tokens per tile
constexpr int NTILES = B_TOK / TM;         // 8192, exact

// packed-weight layout in d_ws (ushort element offsets)
constexpr size_t PW1_OFF   = 0;            // fe_w1: 4kt*16nt*64lane*8 = 32768 el
constexpr size_t PW2_OFF   = 32768;        // fe_w2: 8kt*8nt*64*8      = 32768 el
constexpr size_t PE1_OFF   = 65536;        // ew1:   3 * 6kt*16nt*64*8 = 147456 el
constexpr size_t PE1_PER_R = 49152;
// total ws = 212992 ushort = 425,984 bytes

static __device__ __forceinline__ ushort f2bf(float f) {  // RNE (repack only)
    union { float f; unsigned int i; } x; x.f = f;
    unsigned int i = x.i;
    i += 0x7fffu + ((i >> 16) & 1u);
    return (ushort)(i >> 16);
}

// HW packed f32->bf16 (RNE): D[15:0]=bf16(lo), D[31:16]=bf16(hi)
static __device__ __forceinline__ unsigned pk_bf16(float lo, float hi) {
    unsigned r;
    asm("v_cvt_pk_bf16_f32 %0, %1, %2" : "=v"(r) : "v"(lo), "v"(hi));
    return r;
}

static __device__ __forceinline__ short8 pack8(f32x4 f0, f32x4 f1) {
    union { unsigned u[4]; short8 s; } r;
    r.u[0] = pk_bf16(f0[0], f0[1]);
    r.u[1] = pk_bf16(f0[2], f0[3]);
    r.u[2] = pk_bf16(f1[0], f1[1]);
    r.u[3] = pk_bf16(f1[2], f1[3]);
    return r.s;
}

// swizzled byte offset into the [64][256]-ushort tile (row stride 512B).
// XOR of byte bits 4-6 with row&7: b128 reads at fixed column spread 16
// consecutive rows across all 8 bank groups (2-way max aliasing = free).
static __device__ __forceinline__ int swz(int row, int inb) {
    return (row * 512 + inb) ^ ((row & 7) << 4);
}

// ---- weight repack: fp32 -> bf16 MFMA B-fragment layout -------------------
// pw[frag=kt*NT+nt][lane][j] = bf16(W[kt*32 + (lane>>4)*8 + j][nt*16 + (lane&15)])
__global__ void repack_weights(const float* __restrict__ w1,
                               const float* __restrict__ w2,
                               const float* __restrict__ e1,
                               ushort* __restrict__ pw) {
    int t = blockIdx.x * 256 + threadIdx.x;       // 26624 threads total
    const float* src; int N, kt, nt; size_t dst;
    int lane = t & 63;
    if (t < 4096) {                                // fe_w1: K=128,N=256
        int frag = t >> 6; kt = frag >> 4; nt = frag & 15;
        src = w1; N = 256; dst = PW1_OFF + (size_t)t * 8;
    } else if (t < 8192) {                         // fe_w2: K=256,N=128
        int u = t - 4096; int frag = u >> 6; kt = frag >> 3; nt = frag & 7;
        src = w2; N = 128; dst = PW2_OFF + (size_t)u * 8;
    } else {                                       // ew1[r]: K=192,N=256
        int u = t - 8192; int reg = u / 6144; int v = u % 6144;
        int frag = v >> 6; kt = frag >> 4; nt = frag & 15;
        src = e1 + (size_t)reg * (192 * 256); N = 256;
        dst = PE1_OFF + (size_t)reg * PE1_PER_R + (size_t)v * 8;
    }
    int quad = lane >> 4, cc = lane & 15;
    int k0 = kt * 32 + quad * 8;
    int n  = nt * 16 + cc;
    short8 vv;
    #pragma unroll
    for (int j = 0; j < 8; ++j) vv[j] = (short)f2bf(src[(size_t)(k0 + j) * N + n]);
    *(short8*)(pw + dst) = vv;
}

// ---- fused main: 64 tokens per block, 512 threads = 8 waves ---------------
// Wave w owns a 32-col slice of stage-1/3 outputs and a 16-col slice of
// stage-2; all waves read the full shared A tile from LDS.
__global__ __launch_bounds__(512, 4) void fused_main(
    const float* __restrict__ x,
    const int*   __restrict__ rid,
    const ushort* __restrict__ pw,
    const float* __restrict__ fe_b1,
    const float* __restrict__ fe_b2,
    const float* __restrict__ emb,
    const float* __restrict__ eb1,
    const float* __restrict__ ew2,
    const float* __restrict__ eb2,
    float*       __restrict__ out) {
    __shared__ ushort sBuf[64 * 256];   // 32768 B: X tile -> H tile -> C tile
    __shared__ float  sRed[64][8];      // 2 KB per-wave partials for final dot

    const int t    = threadIdx.x;
    const int w    = t >> 6;
    const int lane = t & 63;
    const int quad = lane >> 4;
    const int c    = lane & 15;
    const int ts   = blockIdx.x * TM;

    // ---- stage X into LDS, UNSORTED (token rows), swizzled ----
    #pragma unroll
    for (int it = 0; it < 2; ++it) {
        int chunk = it * 512 + t;
        int row = chunk >> 4, seg = chunk & 15;   // 8 floats per chunk
        const float* xr = x + (size_t)(ts + row) * 128 + seg * 8;
        f32x4 f0 = *(const f32x4*)xr;
        f32x4 f1 = *(const f32x4*)(xr + 4);
        *(short8*)((char*)sBuf + swz(row, seg * 16)) = pack8(f0, f1);
    }

    // ---- per-wave (redundant, uniform) counting sort of the 64 tokens ----
    // lane l = token l. slot = sorted position of token l. b1/b2 = bounds.
    int slot, b1, b2, tos;
    {
        int myr = rid[ts + lane];
        unsigned long long below = (1ull << lane) - 1ull;
        int base = 0, bb1 = 0, bb2 = 0;
        slot = 0;
        #pragma unroll
        for (int r = 0; r < 3; ++r) {
            unsigned long long mask = __ballot(myr == r);
            if (myr == r) slot = base + __popcll(mask & below);
            base += __popcll(mask);
            if (r == 0) bb1 = base;
            if (r == 1) bb2 = base;
        }
        b1 = __builtin_amdgcn_readfirstlane(bb1);
        b2 = __builtin_amdgcn_readfirstlane(bb2);
        // inverse perm: lane s receives token index whose slot == s
        tos = __builtin_amdgcn_ds_permute(slot << 2, lane);
    }
    __syncthreads();   // X visible to all waves

    // ---- stage 1: H = relu(X @ W1 + b1); wave cols [w*32, w*32+32) ----
    f32x4 acc1[4][2] = {};
    #pragma unroll
    for (int kt = 0; kt < 4; ++kt) {
        short8 a[4], b[2];
        #pragma unroll
        for (int m = 0; m < 4; ++m)
            a[m] = *(const short8*)((const char*)sBuf +
                    swz(m * 16 + c, kt * 64 + quad * 16));
        #pragma unroll
        for (int nn = 0; nn < 2; ++nn)
            b[nn] = *(const short8*)(pw + PW1_OFF +
                    ((size_t)((kt * 16 + (w * 2 + nn)) * 64 + lane)) * 8);
        #pragma unroll
        for (int m = 0; m < 4; ++m)
            #pragma unroll
            for (int nn = 0; nn < 2; ++nn)
                acc1[m][nn] = MFMA16(a[m], b[nn], acc1[m][nn], 0, 0, 0);
    }
    __syncthreads();   // all waves done reading X; acc1 carried in regs

    // epilogue: bias+relu, pack, write H (overwrites X region)
    #pragma unroll
    for (int nn = 0; nn < 2; ++nn) {
        float bb = fe_b1[w * 32 + nn * 16 + c];
        #pragma unroll
        for (int m = 0; m < 4; ++m) {
            int col = w * 32 + nn * 16 + c;
            int r0  = m * 16 + quad * 4;
            float v0 = fmaxf(acc1[m][nn][0] + bb, 0.0f);
            float v1 = fmaxf(acc1[m][nn][1] + bb, 0.0f);
            float v2 = fmaxf(acc1[m][nn][2] + bb, 0.0f);
            float v3 = fmaxf(acc1[m][nn][3] + bb, 0.0f);
            unsigned p01 = pk_bf16(v0, v1);
            unsigned p23 = pk_bf16(v2, v3);
            *(ushort*)((char*)sBuf + swz(r0 + 0, col * 2)) = (ushort)p01;
            *(ushort*)((char*)sBuf + swz(r0 + 1, col * 2)) = (ushort)(p01 >> 16);
            *(ushort*)((char*)sBuf + swz(r0 + 2, col * 2)) = (ushort)p23;
            *(ushort*)((char*)sBuf + swz(r0 + 3, col * 2)) = (ushort)(p23 >> 16);
        }
    }
    __syncthreads();   // H visible

    // ---- stage 2: F = relu(H @ W2 + b2); wave cols [w*16, w*16+16) ----
    f32x4 acc2[4] = {};
    #pragma unroll
    for (int kt = 0; kt < 8; ++kt) {
        short8 a[4];
        #pragma unroll
        for (int m = 0; m < 4; ++m)
            a[m] = *(const short8*)((const char*)sBuf +
                    swz(m * 16 + c, kt * 64 + quad * 16));
        short8 b = *(const short8*)(pw + PW2_OFF +
                ((size_t)((kt * 8 + w) * 64 + lane)) * 8);
        #pragma unroll
        for (int m = 0; m < 4; ++m)
            acc2[m] = MFMA16(a[m], b, acc2[m], 0, 0, 0);
    }
    __syncthreads();   // all waves done reading H; acc2 carried in regs

    // F-write: token-space results scattered to SLOT rows (ds_bpermute gives
    // slotOfToken). Downstream stage-3 reads are then regular/conflict-free.
    {
        float bb = fe_b2[w * 16 + c];
        #pragma unroll
        for (int m = 0; m < 4; ++m) {
            int sr[4];
            #pragma unroll
            for (int i = 0; i < 4; ++i)
                sr[i] = __builtin_amdgcn_ds_bpermute((m * 16 + quad * 4 + i) << 2, slot);
            int col = w * 16 + c;
            float v0 = fmaxf(acc2[m][0] + bb, 0.0f);
            float v1 = fmaxf(acc2[m][1] + bb, 0.0f);
            float v2 = fmaxf(acc2[m][2] + bb, 0.0f);
            float v3 = fmaxf(acc2[m][3] + bb, 0.0f);
            unsigned p01 = pk_bf16(v0, v1);
            unsigned p23 = pk_bf16(v2, v3);
            *(ushort*)((char*)sBuf + swz(sr[0], col * 2)) = (ushort)p01;
            *(ushort*)((char*)sBuf + swz(sr[1], col * 2)) = (ushort)(p01 >> 16);
            *(ushort*)((char*)sBuf + swz(sr[2], col * 2)) = (ushort)p23;
            *(ushort*)((char*)sBuf + swz(sr[3], col * 2)) = (ushort)(p23 >> 16);
        }
    }
    // append per-slot-row regime embedding to C cols [128,192)
    {
        int row = t >> 3, seg = t & 7;            // 512 chunks, 1 iter
        int rr = (row >= b1) + (row >= b2);
        const float* ep = emb + rr * 64 + seg * 8;
        f32x4 f0 = *(const f32x4*)ep;
        f32x4 f1 = *(const f32x4*)(ep + 4);
        *(short8*)((char*)sBuf + swz(row, 256 + seg * 16)) = pack8(f0, f1);
    }
    __syncthreads();   // C visible (slot space)

    // ---- stage 3: per regime, per-m-tile passes; wave cols [w*32,w*32+32) --
    for (int r = 0; r < 3; ++r) {
        int lo = (r == 0) ? 0  : (r == 1 ? b1 : b2);
        int hi = (r == 0) ? b1 : (r == 1 ? b2 : 64);
        if (lo >= hi) continue;               // block-uniform
        const ushort* pe = pw + PE1_OFF + (size_t)r * PE1_PER_R;
        float eb1v[2], w2v[2];
        #pragma unroll
        for (int nn = 0; nn < 2; ++nn) {
            int col = w * 32 + nn * 16 + c;
            eb1v[nn] = eb1[r * 256 + col];
            w2v[nn]  = ew2[r * 256 + col];
        }
        int mlo = lo >> 4, mhi = (hi - 1) >> 4;
        for (int m = mlo; m <= mhi; ++m) {    // block-uniform
            f32x4 acc[2] = {};
            #pragma unroll
            for (int kt = 0; kt < 6; ++kt) {
                short8 a = *(const short8*)((const char*)sBuf +
                        swz(m * 16 + c, kt * 64 + quad * 16));
                #pragma unroll
                for (int nn = 0; nn < 2; ++nn) {
                    short8 b = *(const short8*)(pe +
                            ((size_t)((kt * 16 + (w * 2 + nn)) * 64 + lane)) * 8);
                    acc[nn] = MFMA16(a, b, acc[nn], 0, 0, 0);
                }
            }
            float s[4] = {0.f, 0.f, 0.f, 0.f};
            #pragma unroll
            for (int nn = 0; nn < 2; ++nn)
                #pragma unroll
                for (int i = 0; i < 4; ++i)
                    s[i] += fmaxf(acc[nn][i] + eb1v[nn], 0.0f) * w2v[nn];
            #pragma unroll
            for (int i = 0; i < 4; ++i) {     // reduce over 16 cols (lane bits 0..3)
                s[i] += __shfl_xor(s[i], 1);
                s[i] += __shfl_xor(s[i], 2);
                s[i] += __shfl_xor(s[i], 4);
                s[i] += __shfl_xor(s[i], 8);
            }
            if (c == 0) {
                #pragma unroll
                for (int i = 0; i < 4; ++i) {
                    int row = m * 16 + quad * 4 + i;
                    if (row >= lo && row < hi) sRed[row][w] = s[i];
                }
            }
        }
    }
    __syncthreads();

    // ---- final: sum 8 wave-partials + eb2[regime], scatter fp32 out ----
    if (t < 64) {                              // wave 0: lane t = slot t
        int rr = (t >= b1) + (t >= b2);
        f32x4 r0 = *(const f32x4*)(&sRed[t][0]);
        f32x4 r1 = *(const f32x4*)(&sRed[t][4]);
        float sum = (r0[0] + r0[1]) + (r0[2] + r0[3])
                  + (r1[0] + r1[1]) + (r1[2] + r1[3]) + eb2[rr];
        out[ts + tos] = sum;
    }
}

extern "C" void kernel_launch(void* const* d_in, const int* in_sizes, int n_in,
                              void* d_out, int out_size, void* d_ws, size_t ws_size,
                              hipStream_t stream) {
    const float* x     = (const float*)d_in[0];
    const int*   rid   = (const int*)d_in[1];
    const float* fe_w1 = (const float*)d_in[2];
    const float* fe_b1 = (const float*)d_in[3];
    const float* fe_w2 = (const float*)d_in[4];
    const float* fe_b2 = (const float*)d_in[5];
    const float* emb   = (const float*)d_in[6];
    const float* ew1   = (const float*)d_in[7];
    const float* eb1   = (const float*)d_in[8];
    const float* ew2   = (const float*)d_in[9];
    const float* eb2   = (const float*)d_in[10];
    float* out = (float*)d_out;
    ushort* pw = (ushort*)d_ws;   // 425,984 bytes used

    hipLaunchKernelGGL(repack_weights, dim3(104), dim3(256), 0, stream,
                       fe_w1, fe_w2, ew1, pw);
    hipLaunchKernelGGL(fused_main, dim3(NTILES), dim3(512), 0, stream,
                       x, rid, pw, fe_b1, fe_b2, emb, eb1, ew2, eb2, out);
}

// Round 5
// 493.065 us; speedup vs baseline: 1.4424x; 1.0703x over previous
//
#include <hip/hip_runtime.h>

// RegimeAwareStudent: B=524288 tokens, ALL tensors fp32 (per reference), rid int32.
//   h  = relu(x @ fe_w1 + fe_b1)           [B,128]->[B,256]
//   f  = relu(h @ fe_w2 + fe_b2)           [B,256]->[B,128]
//   c  = concat(f, emb[rid])               [B,192]
//   eh = relu(c @ ew1[rid] + eb1[rid])     [B,192]->[B,256]
//   o  = eh @ ew2[rid] + eb2[rid]          [B,256]->[B,1]
// bf16 MFMA path (RNE at staging), fp32 accumulate, fp32 out.
// R5 vs R4 (288us, 8 waves: LDS traffic scales with waves -> conflicts 2.4e7)
// and R1 (247us, 4 waves, 6 barriers, 2.5 blocks/CU):
//   * 4 waves again (halves LDS re-read traffic vs R4), but SEPARATE X/H LDS
//     regions: each stage writes its own region -> no write-after-read
//     hazard -> 6 barriers -> 4, and NO accumulators live across barriers
//     (the spill cause in R2/R3).
//   * emb never materialized in LDS: within a regime group every C-row has
//     the same emb vector, so the stage-3 A-frag for k in [128,192) is
//     row-independent -> built once per regime from 2 broadcast global
//     loads. Stage-3 LDS reads drop 6->4 per m-pass; append phase gone.
//   * LDS = 16K(X/F) + 32K(H) + 1K(red) = 49.25KB -> 3 blocks/CU at
//     launch_bounds(256,3) (170-reg cap, structural peak ~120 -> no spill).

typedef short short8 __attribute__((ext_vector_type(8)));
typedef float f32x4  __attribute__((ext_vector_type(4)));

#define MFMA16 __builtin_amdgcn_mfma_f32_16x16x32_bf16

constexpr int B_TOK  = 524288;
constexpr int TM     = 64;                 // tokens per tile
constexpr int NTILES = B_TOK / TM;         // 8192, exact

// packed-weight layout in d_ws (ushort element offsets)
constexpr size_t PW1_OFF   = 0;            // fe_w1: 4kt*16nt*64lane*8 = 32768 el
constexpr size_t PW2_OFF   = 32768;        // fe_w2: 8kt*8nt*64*8      = 32768 el
constexpr size_t PE1_OFF   = 65536;        // ew1:   3 * 6kt*16nt*64*8 = 147456 el
constexpr size_t PE1_PER_R = 49152;
// total ws = 212992 ushort = 425,984 bytes

static __device__ __forceinline__ ushort f2bf(float f) {  // RNE (repack only)
    union { float f; unsigned int i; } x; x.f = f;
    unsigned int i = x.i;
    i += 0x7fffu + ((i >> 16) & 1u);
    return (ushort)(i >> 16);
}

// HW packed f32->bf16 (RNE): D[15:0]=bf16(lo), D[31:16]=bf16(hi)
static __device__ __forceinline__ unsigned pk_bf16(float lo, float hi) {
    unsigned r;
    asm("v_cvt_pk_bf16_f32 %0, %1, %2" : "=v"(r) : "v"(lo), "v"(hi));
    return r;
}

static __device__ __forceinline__ short8 pack8(f32x4 f0, f32x4 f1) {
    union { unsigned u[4]; short8 s; } r;
    r.u[0] = pk_bf16(f0[0], f0[1]);
    r.u[1] = pk_bf16(f0[2], f0[3]);
    r.u[2] = pk_bf16(f1[0], f1[1]);
    r.u[3] = pk_bf16(f1[2], f1[3]);
    return r.s;
}

// X/F tile [64][128] bf16, row stride 256B. XOR row&15 into byte bits 4-7:
// 16 rows of a column-read spread over all 16 16B-slots -> balanced banks.
static __device__ __forceinline__ int swzX(int row, int inb) {
    return row * 256 + (inb ^ ((row & 15) << 4));
}
// H tile [64][256] bf16, row stride 512B. XOR row&7 into byte bits 4-6.
static __device__ __forceinline__ int swzH(int row, int inb) {
    return row * 512 + (inb ^ ((row & 7) << 4));
}

// ---- weight repack: fp32 -> bf16 MFMA B-fragment layout -------------------
// pw[frag=kt*NT+nt][lane][j] = bf16(W[kt*32 + (lane>>4)*8 + j][nt*16 + (lane&15)])
__global__ void repack_weights(const float* __restrict__ w1,
                               const float* __restrict__ w2,
                               const float* __restrict__ e1,
                               ushort* __restrict__ pw) {
    int t = blockIdx.x * 256 + threadIdx.x;       // 26624 threads total
    const float* src; int N, kt, nt; size_t dst;
    int lane = t & 63;
    if (t < 4096) {                                // fe_w1: K=128,N=256
        int frag = t >> 6; kt = frag >> 4; nt = frag & 15;
        src = w1; N = 256; dst = PW1_OFF + (size_t)t * 8;
    } else if (t < 8192) {                         // fe_w2: K=256,N=128
        int u = t - 4096; int frag = u >> 6; kt = frag >> 3; nt = frag & 7;
        src = w2; N = 128; dst = PW2_OFF + (size_t)u * 8;
    } else {                                       // ew1[r]: K=192,N=256
        int u = t - 8192; int reg = u / 6144; int v = u % 6144;
        int frag = v >> 6; kt = frag >> 4; nt = frag & 15;
        src = e1 + (size_t)reg * (192 * 256); N = 256;
        dst = PE1_OFF + (size_t)reg * PE1_PER_R + (size_t)v * 8;
    }
    int quad = lane >> 4, cc = lane & 15;
    int k0 = kt * 32 + quad * 8;
    int n  = nt * 16 + cc;
    short8 vv;
    #pragma unroll
    for (int j = 0; j < 8; ++j) vv[j] = (short)f2bf(src[(size_t)(k0 + j) * N + n]);
    *(short8*)(pw + dst) = vv;
}

// ---- fused main: 64 tokens per block, 256 threads = 4 waves ---------------
__global__ __launch_bounds__(256, 3) void fused_main(
    const float* __restrict__ x,
    const int*   __restrict__ rid,
    const ushort* __restrict__ pw,
    const float* __restrict__ fe_b1,
    const float* __restrict__ fe_b2,
    const float* __restrict__ emb,
    const float* __restrict__ eb1,
    const float* __restrict__ ew2,
    const float* __restrict__ eb2,
    float*       __restrict__ out) {
    __shared__ ushort sX[64 * 128];    // 16 KB: X tile, then F tile (slot rows)
    __shared__ ushort sH[64 * 256];    // 32 KB: H tile
    __shared__ float  sRed[64][4];     // 1 KB: per-wave partials

    const int t    = threadIdx.x;
    const int w    = t >> 6;
    const int lane = t & 63;
    const int quad = lane >> 4;
    const int c    = lane & 15;
    const int ts   = blockIdx.x * TM;

    // ---- stage X into LDS, UNSORTED (token rows), swizzled ----
    #pragma unroll
    for (int it = 0; it < 4; ++it) {
        int chunk = it * 256 + t;
        int row = chunk >> 4, seg = chunk & 15;   // 8 floats per chunk
        const float* xr = x + (size_t)(ts + row) * 128 + seg * 8;
        f32x4 f0 = *(const f32x4*)xr;
        f32x4 f1 = *(const f32x4*)(xr + 4);
        *(short8*)((char*)sX + swzX(row, seg * 16)) = pack8(f0, f1);
    }

    // ---- per-wave (redundant, uniform) counting sort of the 64 tokens ----
    int slot, b1, b2, tos;
    {
        int myr = rid[ts + lane];
        unsigned long long below = (1ull << lane) - 1ull;
        int base = 0, bb1 = 0, bb2 = 0;
        slot = 0;
        #pragma unroll
        for (int r = 0; r < 3; ++r) {
            unsigned long long mask = __ballot(myr == r);
            if (myr == r) slot = base + __popcll(mask & below);
            base += __popcll(mask);
            if (r == 0) bb1 = base;
            if (r == 1) bb2 = base;
        }
        b1 = __builtin_amdgcn_readfirstlane(bb1);
        b2 = __builtin_amdgcn_readfirstlane(bb2);
        tos = __builtin_amdgcn_ds_permute(slot << 2, lane);  // slot s -> token
    }
    __syncthreads();   // (1) X visible

    // ---- stage 1: H = relu(X @ W1 + b1); wave cols [w*64, w*64+64) ----
    // reads sX, writes sH (separate region -> no barrier before writes)
    {
        f32x4 acc[4][4] = {};
        #pragma unroll
        for (int kt = 0; kt < 4; ++kt) {
            short8 a[4], b[4];
            #pragma unroll
            for (int m = 0; m < 4; ++m)
                a[m] = *(const short8*)((const char*)sX +
                        swzX(m * 16 + c, kt * 64 + quad * 16));
            #pragma unroll
            for (int nn = 0; nn < 4; ++nn)
                b[nn] = *(const short8*)(pw + PW1_OFF +
                        ((size_t)((kt * 16 + (w * 4 + nn)) * 64 + lane)) * 8);
            #pragma unroll
            for (int m = 0; m < 4; ++m)
                #pragma unroll
                for (int nn = 0; nn < 4; ++nn)
                    acc[m][nn] = MFMA16(a[m], b[nn], acc[m][nn], 0, 0, 0);
        }
        #pragma unroll
        for (int nn = 0; nn < 4; ++nn) {
            float bb = fe_b1[w * 64 + nn * 16 + c];
            #pragma unroll
            for (int m = 0; m < 4; ++m) {
                int col = w * 64 + nn * 16 + c;
                int r0  = m * 16 + quad * 4;
                float v0 = fmaxf(acc[m][nn][0] + bb, 0.0f);
                float v1 = fmaxf(acc[m][nn][1] + bb, 0.0f);
                float v2 = fmaxf(acc[m][nn][2] + bb, 0.0f);
                float v3 = fmaxf(acc[m][nn][3] + bb, 0.0f);
                unsigned p01 = pk_bf16(v0, v1);
                unsigned p23 = pk_bf16(v2, v3);
                *(ushort*)((char*)sH + swzH(r0 + 0, col * 2)) = (ushort)p01;
                *(ushort*)((char*)sH + swzH(r0 + 1, col * 2)) = (ushort)(p01 >> 16);
                *(ushort*)((char*)sH + swzH(r0 + 2, col * 2)) = (ushort)p23;
                *(ushort*)((char*)sH + swzH(r0 + 3, col * 2)) = (ushort)(p23 >> 16);
            }
        }
    }
    __syncthreads();   // (2) H visible; X dead (everyone past stage-1 reads)

    // ---- stage 2: F = relu(H @ W2 + b2); wave cols [w*32, w*32+32) ----
    // reads sH, writes F into sX region, slot-scattered via ds_bpermute.
    {
        f32x4 acc[4][2] = {};
        #pragma unroll
        for (int kt = 0; kt < 8; ++kt) {
            short8 a[4], b[2];
            #pragma unroll
            for (int m = 0; m < 4; ++m)
                a[m] = *(const short8*)((const char*)sH +
                        swzH(m * 16 + c, kt * 64 + quad * 16));
            #pragma unroll
            for (int nn = 0; nn < 2; ++nn)
                b[nn] = *(const short8*)(pw + PW2_OFF +
                        ((size_t)((kt * 8 + (w * 2 + nn)) * 64 + lane)) * 8);
            #pragma unroll
            for (int m = 0; m < 4; ++m)
                #pragma unroll
                for (int nn = 0; nn < 2; ++nn)
                    acc[m][nn] = MFMA16(a[m], b[nn], acc[m][nn], 0, 0, 0);
        }
        float b2v[2];
        #pragma unroll
        for (int nn = 0; nn < 2; ++nn) b2v[nn] = fe_b2[w * 32 + nn * 16 + c];
        #pragma unroll
        for (int m = 0; m < 4; ++m) {
            int sr[4];
            #pragma unroll
            for (int i = 0; i < 4; ++i)
                sr[i] = __builtin_amdgcn_ds_bpermute((m * 16 + quad * 4 + i) << 2, slot);
            #pragma unroll
            for (int nn = 0; nn < 2; ++nn) {
                int col = w * 32 + nn * 16 + c;
                float v0 = fmaxf(acc[m][nn][0] + b2v[nn], 0.0f);
                float v1 = fmaxf(acc[m][nn][1] + b2v[nn], 0.0f);
                float v2 = fmaxf(acc[m][nn][2] + b2v[nn], 0.0f);
                float v3 = fmaxf(acc[m][nn][3] + b2v[nn], 0.0f);
                unsigned p01 = pk_bf16(v0, v1);
                unsigned p23 = pk_bf16(v2, v3);
                *(ushort*)((char*)sX + swzX(sr[0], col * 2)) = (ushort)p01;
                *(ushort*)((char*)sX + swzX(sr[1], col * 2)) = (ushort)(p01 >> 16);
                *(ushort*)((char*)sX + swzX(sr[2], col * 2)) = (ushort)p23;
                *(ushort*)((char*)sX + swzX(sr[3], col * 2)) = (ushort)(p23 >> 16);
            }
        }
    }
    __syncthreads();   // (3) F visible (slot space); H dead

    // ---- stage 3: per regime, per-m-tile passes; wave cols [w*64,w*64+64) --
    // C = [F | emb_r]: kt=0..3 A-frag from sX; kt=4,5 A-frag is ROW-INDEPENDENT
    // (same emb vector for the whole regime group) -> built once per regime
    // from broadcast global loads. B-frags from packed ew1[r].
    for (int r = 0; r < 3; ++r) {
        int lo = (r == 0) ? 0  : (r == 1 ? b1 : b2);
        int hi = (r == 0) ? b1 : (r == 1 ? b2 : 64);
        if (lo >= hi) continue;               // block-uniform
        const ushort* pe = pw + PE1_OFF + (size_t)r * PE1_PER_R;
        // emb A-fragments for kt=4,5 (uniform across rows/c-lanes)
        short8 aEmb[2];
        #pragma unroll
        for (int e = 0; e < 2; ++e) {
            const float* ep = emb + r * 64 + e * 32 + quad * 8;
            f32x4 f0 = *(const f32x4*)ep;
            f32x4 f1 = *(const f32x4*)(ep + 4);
            aEmb[e] = pack8(f0, f1);
        }
        float eb1v[4], w2v[4];
        #pragma unroll
        for (int nn = 0; nn < 4; ++nn) {
            int col = w * 64 + nn * 16 + c;
            eb1v[nn] = eb1[r * 256 + col];
            w2v[nn]  = ew2[r * 256 + col];
        }
        int mlo = lo >> 4, mhi = (hi - 1) >> 4;
        for (int m = mlo; m <= mhi; ++m) {    // block-uniform
            f32x4 acc[4] = {};
            #pragma unroll
            for (int kt = 0; kt < 6; ++kt) {
                short8 a;
                if (kt < 4)
                    a = *(const short8*)((const char*)sX +
                            swzX(m * 16 + c, kt * 64 + quad * 16));
                else
                    a = aEmb[kt - 4];
                #pragma unroll
                for (int nn = 0; nn < 4; ++nn) {
                    short8 b = *(const short8*)(pe +
                            ((size_t)((kt * 16 + (w * 4 + nn)) * 64 + lane)) * 8);
                    acc[nn] = MFMA16(a, b, acc[nn], 0, 0, 0);
                }
            }
            float s[4] = {0.f, 0.f, 0.f, 0.f};
            #pragma unroll
            for (int nn = 0; nn < 4; ++nn)
                #pragma unroll
                for (int i = 0; i < 4; ++i)
                    s[i] += fmaxf(acc[nn][i] + eb1v[nn], 0.0f) * w2v[nn];
            #pragma unroll
            for (int i = 0; i < 4; ++i) {     // reduce over 16 cols (lane bits 0..3)
                s[i] += __shfl_xor(s[i], 1);
                s[i] += __shfl_xor(s[i], 2);
                s[i] += __shfl_xor(s[i], 4);
                s[i] += __shfl_xor(s[i], 8);
            }
            if (c == 0) {
                #pragma unroll
                for (int i = 0; i < 4; ++i) {
                    int row = m * 16 + quad * 4 + i;
                    if (row >= lo && row < hi) sRed[row][w] = s[i];
                }
            }
        }
    }
    __syncthreads();   // (4) partials visible

    // ---- final: sum 4 wave-partials + eb2[regime], scatter fp32 out ----
    if (t < 64) {                              // wave 0: lane t = slot t
        int rr = (t >= b1) + (t >= b2);
        f32x4 rv = *(const f32x4*)(&sRed[t][0]);
        out[ts + tos] = rv[0] + rv[1] + rv[2] + rv[3] + eb2[rr];
    }
}

extern "C" void kernel_launch(void* const* d_in, const int* in_sizes, int n_in,
                              void* d_out, int out_size, void* d_ws, size_t ws_size,
                              hipStream_t stream) {
    const float* x     = (const float*)d_in[0];
    const int*   rid   = (const int*)d_in[1];
    const float* fe_w1 = (const float*)d_in[2];
    const float* fe_b1 = (const float*)d_in[3];
    const float* fe_w2 = (const float*)d_in[4];
    const float* fe_b2 = (const float*)d_in[5];
    const float* emb   = (const float*)d_in[6];
    const float* ew1   = (const float*)d_in[7];
    const float* eb1   = (const float*)d_in[8];
    const float* ew2   = (const float*)d_in[9];
    const float* eb2   = (const float*)d_in[10];
    float* out = (float*)d_out;
    ushort* pw = (ushort*)d_ws;   // 425,984 bytes used

    hipLaunchKernelGGL(repack_weights, dim3(104), dim3(256), 0, stream,
                       fe_w1, fe_w2, ew1, pw);
    hipLaunchKernelGGL(fused_main, dim3(NTILES), dim3(256), 0, stream,
                       x, rid, pw, fe_b1, fe_b2, emb, eb1, ew2, eb2, out);
}